// Round 7
// baseline (252.061 us; speedup 1.0000x reference)
//
#include <hip/hip_runtime.h>
#include <stdint.h>

#define Bsz  2
#define Tseq 2048
#define Cemb 1024
#define NH   16
#define HD   64

typedef __attribute__((ext_vector_type(8))) __bf16 bf16x8;
typedef __attribute__((ext_vector_type(4))) float  f32x4;
typedef __attribute__((ext_vector_type(8))) unsigned short u16x8;

#define MFMA16(a, b, c) __builtin_amdgcn_mfma_f32_16x16x32_bf16((a), (b), (c), 0, 0, 0)

__device__ __forceinline__ unsigned short f2bf(float f) {
  union { float f; unsigned int u; } v; v.f = f;
  unsigned int u = v.u;
  u += 0x7fffu + ((u >> 16) & 1u);   // RNE; inputs are finite
  return (unsigned short)(u >> 16);
}
__device__ __forceinline__ float bf2f(unsigned short h) {
  union { unsigned int u; float f; } v; v.u = ((unsigned int)h) << 16;
  return v.f;
}
// pack two fp32 -> two bf16 (round-half-up) in one u32: [bf(a) | bf(b)<<16]
__device__ __forceinline__ unsigned int pack_bf2(float a, float b) {
  union { float f; unsigned int u; } va, vb; va.f = a; vb.f = b;
  return __builtin_amdgcn_perm(vb.u + 0x8000u, va.u + 0x8000u, 0x07060302u);
}

typedef __attribute__((address_space(1))) const unsigned int GU;
typedef __attribute__((address_space(3))) unsigned int LU;
__device__ __forceinline__ void load_lds16(const void* g, void* l) {
  __builtin_amdgcn_global_load_lds((GU*)g, (LU*)l, 16, 0, 0);
}

// ---------------- fused cast fp32 -> bf16 for x, W_attn, W_proj ----------------
#define XE  4194304
#define WAE 3145728
__global__ void cast3_kernel(const float* __restrict__ x,
                             const float* __restrict__ wa,
                             const float* __restrict__ wp,
                             unsigned short* __restrict__ out) {
  const int i = (blockIdx.x * blockDim.x + threadIdx.x) * 4;
  const float* src;
  int off;
  if (i < XE) { src = x; off = i; }
  else if (i < XE + WAE) { src = wa; off = i - XE; }
  else { src = wp; off = i - (XE + WAE); }
  const float4 f = *(const float4*)(src + off);
  ushort4 o;
  o.x = f2bf(f.x); o.y = f2bf(f.y); o.z = f2bf(f.z); o.w = f2bf(f.w);
  *(ushort4*)(out + i) = o;
}

// ---------------- qkv GEMM: x[4096,1024] @ W_attn^T[., 3072] + b ----------------
// BK=32. Writes qkv[3][B][H][T][64]; V additionally transposed to
// vt[B][H][64][T] (gathered from the epilogue LDS tile).
__global__ __launch_bounds__(256) void gemm_qkv_kernel(
    const unsigned short* __restrict__ A,
    const unsigned short* __restrict__ Bw,
    const float* __restrict__ bias,
    unsigned short* __restrict__ qkv,
    unsigned short* __restrict__ vt) {
  const int K = Cemb;
  __shared__ unsigned short sA[128 * 32];
  __shared__ unsigned short sB[128 * 32];
  const int tid = threadIdx.x;
  const int wave = tid >> 6, lane = tid & 63;
  const int quad = lane >> 4, lrow = lane & 15;
  const int l7 = lrow & 7;
  const int wm = (wave >> 1) * 64, wn = (wave & 1) * 64;
  const int tileM = blockIdx.y * 128, tileN = blockIdx.x * 128;

  f32x4 acc[4][4];
#pragma unroll
  for (int i = 0; i < 4; ++i)
#pragma unroll
    for (int j = 0; j < 4; ++j) acc[i][j] = (f32x4){0.f, 0.f, 0.f, 0.f};

  for (int k0 = 0; k0 < K; k0 += 32) {
    __syncthreads();
#pragma unroll
    for (int s = 0; s < 2; ++s) {
      const int cid = tid + s * 256;          // 512 chunks of 16B
      const int r = cid >> 2, ko = (cid & 3) * 8;
      load_lds16(&A[(size_t)(tileM + r) * K + k0 + ko], &sA[cid * 8]);
      load_lds16(&Bw[(size_t)(tileN + r) * K + k0 + ko], &sB[cid * 8]);
    }
    __syncthreads();
    bf16x8 af[4], bfm[4];
#pragma unroll
    for (int mt = 0; mt < 4; ++mt)
      af[mt] = *(const bf16x8*)&sA[(wm + mt * 16 + lrow) * 32 + quad * 8];
#pragma unroll
    for (int nt = 0; nt < 4; ++nt)
      bfm[nt] = *(const bf16x8*)&sB[(wn + nt * 16 + lrow) * 32 + quad * 8];
#pragma unroll
    for (int mt = 0; mt < 4; ++mt)
#pragma unroll
      for (int nt = 0; nt < 4; ++nt)
        acc[mt][nt] = MFMA16(af[mt], bfm[nt], acc[mt][nt]);
  }

  // epilogue: transpose through LDS (reuse sA), coalesced 16B stores.
  __syncthreads();
  unsigned short* sEp = sA + wave * 1024;   // 16 rows x 64 cols, swizzled
  float bias_v[4];
#pragma unroll
  for (int nt = 0; nt < 4; ++nt) bias_v[nt] = bias[tileN + wn + nt * 16 + lrow];
  const int gn0 = tileN + wn;               // 64-aligned -> one (part,h) slab
  const int part = gn0 >> 10, h = (gn0 & 1023) >> 6;

#pragma unroll
  for (int mt = 0; mt < 4; ++mt) {
#pragma unroll
    for (int nt = 0; nt < 4; ++nt)
#pragma unroll
      for (int reg = 0; reg < 4; ++reg) {
        const int q = quad * 4 + reg;
        const int ch = (nt * 2 + (lrow >> 3)) ^ (q & 7);
        sEp[q * 64 + ch * 8 + l7] = f2bf(acc[mt][nt][reg] + bias_v[nt]);
      }
    __builtin_amdgcn_wave_barrier();
#pragma unroll
    for (int i = 0; i < 2; ++i) {
      const int c = i * 64 + lane;
      const int r = c >> 3, ch2 = c & 7;
      const u16x8 row = *(const u16x8*)&sEp[r * 64 + ((ch2 ^ (r & 7)) << 3)];
      const int gm = tileM + wm + mt * 16 + r;
      const int bb = gm >> 11, t = gm & 2047;
      *(u16x8*)&qkv[((((size_t)part * Bsz + bb) * NH + h) * Tseq + t) * HD + ch2 * 8] = row;
    }
    if (part == 2) {
      // V^T store: lane owns d=lane, gathers 16 t-values from the LDS column.
      unsigned int w[8];
#pragma unroll
      for (int q = 0; q < 16; q += 2) {
        const unsigned short a0 =
            sEp[q * 64 + (((lane >> 3) ^ (q & 7)) << 3) + (lane & 7)];
        const unsigned short a1 =
            sEp[(q + 1) * 64 + (((lane >> 3) ^ ((q + 1) & 7)) << 3) + (lane & 7)];
        w[q >> 1] = (unsigned int)a0 | ((unsigned int)a1 << 16);
      }
      const int gm0 = tileM + wm + mt * 16;
      const int bb = gm0 >> 11, t0 = gm0 & 2047;
      unsigned short* dst = &vt[(((size_t)bb * NH + h) * HD + lane) * Tseq + t0];
      *(uint4*)(dst) = *(const uint4*)&w[0];
      *(uint4*)(dst + 8) = *(const uint4*)&w[4];
    }
    __builtin_amdgcn_wave_barrier();
  }
}

// ---------------- proj GEMM: y[4096,1024] @ W_proj^T + b -> out fp32 ----------------
// tile 32(M) x 128(N), BK=32, grid (8,128)=1024 blocks -> 4 blocks/CU.
__global__ __launch_bounds__(256) void gemm_proj_kernel(
    const unsigned short* __restrict__ A,
    const unsigned short* __restrict__ Bw,
    const float* __restrict__ bias,
    float* __restrict__ out) {
  const int K = Cemb;
  __shared__ unsigned short sA[32 * 32];
  __shared__ unsigned short sB[128 * 32];
  const int tid = threadIdx.x;
  const int wave = tid >> 6, lane = tid & 63;
  const int quad = lane >> 4, lrow = lane & 15;
  const int wn = wave * 32;
  const int tileM = blockIdx.y * 32, tileN = blockIdx.x * 128;

  f32x4 acc[2][2];
#pragma unroll
  for (int i = 0; i < 2; ++i)
#pragma unroll
    for (int j = 0; j < 2; ++j) acc[i][j] = (f32x4){0.f, 0.f, 0.f, 0.f};

  for (int k0 = 0; k0 < K; k0 += 32) {
    __syncthreads();
    if (tid < 128) {                                     // 128 A-chunks
      const int r = tid >> 2, ko = (tid & 3) * 8;
      load_lds16(&A[(size_t)(tileM + r) * K + k0 + ko], &sA[tid * 8]);
    }
#pragma unroll
    for (int s = 0; s < 2; ++s) {
      const int cB = tid + s * 256;                      // 512 B-chunks
      const int rB = cB >> 2, koB = (cB & 3) * 8;
      load_lds16(&Bw[(size_t)(tileN + rB) * K + k0 + koB], &sB[cB * 8]);
    }
    __syncthreads();
    bf16x8 af[2], bfm[2];
#pragma unroll
    for (int mt = 0; mt < 2; ++mt)
      af[mt] = *(const bf16x8*)&sA[(mt * 16 + lrow) * 32 + quad * 8];
#pragma unroll
    for (int nt = 0; nt < 2; ++nt)
      bfm[nt] = *(const bf16x8*)&sB[(wn + nt * 16 + lrow) * 32 + quad * 8];
#pragma unroll
    for (int mt = 0; mt < 2; ++mt)
#pragma unroll
      for (int nt = 0; nt < 2; ++nt)
        acc[mt][nt] = MFMA16(af[mt], bfm[nt], acc[mt][nt]);
  }

#pragma unroll
  for (int mt = 0; mt < 2; ++mt)
#pragma unroll
    for (int nt = 0; nt < 2; ++nt)
#pragma unroll
      for (int reg = 0; reg < 4; ++reg) {
        const int gm = tileM + mt * 16 + quad * 4 + reg;
        const int gn = tileN + wn + nt * 16 + lrow;
        out[(size_t)gm * Cemb + gn] = acc[mt][nt][reg] + bias[gn];
      }
}

// ---------------- flash attention: transposed-S, dual q-tiles, KT=128 ----------
// Two 64-key subtiles per barrier: halves barrier count, doubles per-iteration
// independent work. K and V^T staged via global_load_lds (source-permuted XOR
// swizzle, lane-linear dests). St = K·Q^T with permuted K rows so St's
// C-registers ARE the PV B-fragments. O^T = V^T·P^T.
__global__ __launch_bounds__(256) void attn_kernel(
    const unsigned short* __restrict__ qkv,
    const unsigned short* __restrict__ vt,    // [B][H][64][T]
    const float* __restrict__ palpha, const float* __restrict__ pbeta,
    const float* __restrict__ pgamma,
    unsigned short* __restrict__ y) {
  __shared__ unsigned short sK[2][128 * 64];   // row=key (128), 8 chunks of d
  __shared__ unsigned short sVt[2][64 * 128];  // row=d (64), 16 chunks of t

  const int tid = threadIdx.x;
  const int wave = tid >> 6, lane = tid & 63;
  const int quad = lane >> 4, lrow = lane & 15;
  const int bh = blockIdx.y;
  const int b = bh >> 4, h = bh & 15;

  const size_t partStride = (size_t)Bsz * NH * Tseq * HD;
  const size_t headoff = (size_t)bh * Tseq * HD;
  const unsigned short* Q = qkv + headoff;
  const unsigned short* Kp = qkv + partStride + headoff;
  const unsigned short* Vp = qkv + 2 * partStride + headoff;
  const unsigned short* Vt_g = vt + (size_t)bh * HD * Tseq;

  const float alpha = palpha[0], beta = pbeta[0], gamma = pgamma[0];
  const float SCL = 0.125f * 1.44269504089f;   // /sqrt(d) * log2(e)

  union { unsigned short u[8]; bf16x8 v; } onesU;
#pragma unroll
  for (int j = 0; j < 8; ++j) onesU.u[j] = 0x3F80;  // bf16 1.0
  const bf16x8 onesF = onesU.v;

  const int qtA = blockIdx.x;          // 0..15
  const int qtB = 31 - qtA;            // 16..31
  const int q0A = qtA * 64, q0B = qtB * 64;

  // Q fragments as B operands: B[k=d=quad*8+j][n=q=lrow]
  const int qrowA = q0A + wave * 16 + lrow;
  const int qrowB = q0B + wave * 16 + lrow;
  const bf16x8 bQA0 = *(const bf16x8*)&Q[(size_t)qrowA * HD + quad * 8];
  const bf16x8 bQA1 = *(const bf16x8*)&Q[(size_t)qrowA * HD + 32 + quad * 8];
  const bf16x8 bQB0 = *(const bf16x8*)&Q[(size_t)qrowB * HD + quad * 8];
  const bf16x8 bQB1 = *(const bf16x8*)&Q[(size_t)qrowB * HD + 32 + quad * 8];

  // permuted K-row base: prow = 2*(m&~3)+(m&3) for m=lrow
  const int prow = ((lrow & 12) << 1) | (lrow & 3);

  f32x4 OtA[4], UtA[4], LA, OtB[4], UtB[4], LB;
#pragma unroll
  for (int dt = 0; dt < 4; ++dt) {
    OtA[dt] = (f32x4){0.f, 0.f, 0.f, 0.f};
    UtA[dt] = (f32x4){0.f, 0.f, 0.f, 0.f};
    OtB[dt] = (f32x4){0.f, 0.f, 0.f, 0.f};
    UtB[dt] = (f32x4){0.f, 0.f, 0.f, 0.f};
  }
  LA = (f32x4){0.f, 0.f, 0.f, 0.f};
  LB = (f32x4){0.f, 0.f, 0.f, 0.f};

  // DMA staging: per 128-key pair, K = 1024 chunks (row r 0..127, 8 chunks),
  // V^T = 1024 chunks (row d 0..63, 16 chunks). Source-permuted XOR swizzle,
  // lane-linear dests (DMA-legal). h(r) = (r&7)^((r&16)>>2).
  auto stage_tile = [&](int ip, int buf) {
    const int j0 = ip * 128;
#pragma unroll
    for (int s = 0; s < 4; ++s) {
      const int c = tid + s * 256;
      const int r = c >> 3, cc = c & 7;
      const int pk = cc ^ (r & 7) ^ ((r & 16) >> 2);
      load_lds16(&Kp[(size_t)(j0 + r) * HD + pk * 8], &sK[buf][c * 8]);
    }
#pragma unroll
    for (int s = 0; s < 4; ++s) {
      const int c = tid + s * 256;
      const int r = c >> 4, cc = c & 15;
      const int pk = (cc & 8) | ((cc & 7) ^ (r & 7) ^ ((r & 16) >> 2));
      load_lds16(&Vt_g[(size_t)r * Tseq + j0 + pk * 8], &sVt[buf][c * 8]);
    }
  };

  stage_tile(0, 0);

  const int npairs = (qtB + 2) >> 1;   // ceil((qtB+1)/2)
  for (int ip = 0; ip < npairs; ++ip) {
    const int cur = ip & 1;
    __syncthreads();                 // drains DMA for pair `ip`, fences readers
    if (ip + 1 < npairs) stage_tile(ip + 1, (ip + 1) & 1);

    const unsigned short* Kb = sK[cur];
    const unsigned short* Vb = sVt[cur];

#pragma unroll
    for (int sub = 0; sub < 2; ++sub) {
      const int tt = ip * 2 + sub;
      if (tt > qtB) continue;
      const unsigned short* K_ = Kb + sub * 64 * 64;
      const int j0 = tt * 64;
      const bool actA = (tt <= qtA);
      const bool diagA = (tt == qtA), diagB = (tt == qtB);

      // QK^T for both chains; K fragment reads shared.
      unsigned int pkA[4][2], pkB[4][2];
#pragma unroll
      for (int ct = 0; ct < 4; ++ct) {
        const int srow = (ct >> 1) * 32 + (ct & 1) * 4 + prow;
        const int hs = (srow & 7) ^ ((srow & 16) >> 2);
        const bf16x8 a0 = *(const bf16x8*)&K_[srow * 64 + ((quad ^ hs) << 3)];
        const bf16x8 a1 = *(const bf16x8*)&K_[srow * 64 + (((4 + quad) ^ hs) << 3)];
        const int sbase = j0 + (ct >> 1) * 32 + (ct & 1) * 4 + quad * 8;

        f32x4 sB = (f32x4){0.f, 0.f, 0.f, 0.f};
        sB = MFMA16(a0, bQB0, sB);
        sB = MFMA16(a1, bQB1, sB);
        float pB[4];
        if (diagB) {
#pragma unroll
          for (int reg = 0; reg < 4; ++reg)
            pB[reg] = exp2f((sbase + reg > qrowB) ? -1e30f : sB[reg] * SCL);
        } else {
#pragma unroll
          for (int reg = 0; reg < 4; ++reg) pB[reg] = exp2f(sB[reg] * SCL);
        }
        pkB[ct][0] = pack_bf2(pB[0], pB[1]);
        pkB[ct][1] = pack_bf2(pB[2], pB[3]);

        if (actA) {
          f32x4 sA = (f32x4){0.f, 0.f, 0.f, 0.f};
          sA = MFMA16(a0, bQA0, sA);
          sA = MFMA16(a1, bQA1, sA);
          float pA[4];
          if (diagA) {
#pragma unroll
            for (int reg = 0; reg < 4; ++reg)
              pA[reg] = exp2f((sbase + reg > qrowA) ? -1e30f : sA[reg] * SCL);
          } else {
#pragma unroll
            for (int reg = 0; reg < 4; ++reg) pA[reg] = exp2f(sA[reg] * SCL);
          }
          pkA[ct][0] = pack_bf2(pA[0], pA[1]);
          pkA[ct][1] = pack_bf2(pA[2], pA[3]);
        }
      }

      union { unsigned int w[4]; bf16x8 v; } tu;
      tu.w[0] = pkB[0][0]; tu.w[1] = pkB[0][1]; tu.w[2] = pkB[1][0]; tu.w[3] = pkB[1][1];
      const bf16x8 P1B = tu.v;
      tu.w[0] = pkB[2][0]; tu.w[1] = pkB[2][1]; tu.w[2] = pkB[3][0]; tu.w[3] = pkB[3][1];
      const bf16x8 P2B = tu.v;
      bf16x8 P1A = onesF, P2A = onesF;
      if (actA) {
        tu.w[0] = pkA[0][0]; tu.w[1] = pkA[0][1]; tu.w[2] = pkA[1][0]; tu.w[3] = pkA[1][1];
        P1A = tu.v;
        tu.w[0] = pkA[2][0]; tu.w[1] = pkA[2][1]; tu.w[2] = pkA[3][0]; tu.w[3] = pkA[3][1];
        P2A = tu.v;
      }

      LB = MFMA16(onesF, P1B, LB);
      LB = MFMA16(onesF, P2B, LB);
      if (actA) {
        LA = MFMA16(onesF, P1A, LA);
        LA = MFMA16(onesF, P2A, LA);
      }

      // masked-ones B operands for U
      bf16x8 u1B = onesF, u2B = onesF, u1A = onesF, u2A = onesF;
      if (diagB) {
        union { unsigned short u[8]; bf16x8 v; } m0, m1;
#pragma unroll
        for (int jj = 0; jj < 8; ++jj) {
          m0.u[jj] = (j0 + quad * 8 + jj) <= qrowB ? (unsigned short)0x3F80 : (unsigned short)0;
          m1.u[jj] = (j0 + 32 + quad * 8 + jj) <= qrowB ? (unsigned short)0x3F80 : (unsigned short)0;
        }
        u1B = m0.v; u2B = m1.v;
      }
      if (actA && diagA) {
        union { unsigned short u[8]; bf16x8 v; } m0, m1;
#pragma unroll
        for (int jj = 0; jj < 8; ++jj) {
          m0.u[jj] = (j0 + quad * 8 + jj) <= qrowA ? (unsigned short)0x3F80 : (unsigned short)0;
          m1.u[jj] = (j0 + 32 + quad * 8 + jj) <= qrowA ? (unsigned short)0x3F80 : (unsigned short)0;
        }
        u1A = m0.v; u2A = m1.v;
      }

      // PV + U for both chains; V fragment reads shared. V chunk base = sub*8.
#pragma unroll
      for (int dt = 0; dt < 4; ++dt) {
        const int vr = dt * 16 + lrow;
        const int hvr = (vr & 7) ^ ((vr & 16) >> 2);
        const bf16x8 av0 = *(const bf16x8*)&Vb[vr * 128 + ((sub * 8 + (quad ^ hvr)) << 3)];
        const bf16x8 av1 = *(const bf16x8*)&Vb[vr * 128 + ((sub * 8 + ((4 + quad) ^ hvr)) << 3)];
        OtB[dt] = MFMA16(av0, P1B, OtB[dt]);
        OtB[dt] = MFMA16(av1, P2B, OtB[dt]);
        UtB[dt] = MFMA16(av0, u1B, UtB[dt]);
        UtB[dt] = MFMA16(av1, u2B, UtB[dt]);
        if (actA) {
          OtA[dt] = MFMA16(av0, P1A, OtA[dt]);
          OtA[dt] = MFMA16(av1, P2A, OtA[dt]);
          UtA[dt] = MFMA16(av0, u1A, UtA[dt]);
          UtA[dt] = MFMA16(av1, u2A, UtA[dt]);
        }
      }
    }
  }

  // epilogue: thread owns q-row, d = dt*16+quad*4+reg
  auto epilogue = [&](const f32x4* Ot, const f32x4* Ut, const f32x4& L, int qrow) {
    const float bl = beta / L[0];
    const float gi = gamma / (float)(qrow + 1);
    const size_t ybase = ((size_t)b * Tseq + qrow) * Cemb + h * HD;
#pragma unroll
    for (int dt = 0; dt < 4; ++dt) {
      const int d0 = dt * 16 + quad * 4;
      const ushort4 vv4 = *(const ushort4*)&Vp[(size_t)qrow * HD + d0];
      const unsigned short vu[4] = {vv4.x, vv4.y, vv4.z, vv4.w};
      ushort4 o;
      unsigned short* op = (unsigned short*)&o;
#pragma unroll
      for (int reg = 0; reg < 4; ++reg) {
        const float yv = bl * Ot[dt][reg] + alpha * bf2f(vu[reg]) - gi * Ut[dt][reg];
        op[reg] = f2bf(yv);
      }
      *(ushort4*)&y[ybase + d0] = o;
    }
  };
  epilogue(OtA, UtA, LA, qrowA);
  epilogue(OtB, UtB, LB, qrowB);
}

// ---------------- host launch ----------------
extern "C" void kernel_launch(void* const* d_in, const int* in_sizes, int n_in,
                              void* d_out, int out_size, void* d_ws, size_t ws_size,
                              hipStream_t stream) {
  const float* x  = (const float*)d_in[0];
  const float* Wa = (const float*)d_in[1];
  const float* ba = (const float*)d_in[2];
  const float* Wp = (const float*)d_in[3];
  const float* bp = (const float*)d_in[4];
  const float* alpha = (const float*)d_in[5];
  const float* beta  = (const float*)d_in[6];
  const float* gamma = (const float*)d_in[7];
  float* out = (float*)d_out;

  unsigned short* ws = (unsigned short*)d_ws;
  unsigned short* xb   = ws;                                   // 4M bf16
  unsigned short* wab  = xb + (size_t)XE;                      // 3M
  unsigned short* wpb  = wab + (size_t)WAE;                    // 1M
  unsigned short* qkvb = wpb + (size_t)1024 * 1024;            // 12M
  unsigned short* yb   = qkvb + (size_t)3 * Bsz * NH * Tseq * HD;  // 4M
  unsigned short* vtb  = yb + (size_t)Bsz * Tseq * Cemb;       // 4M (V^T)

  cast3_kernel<<<(XE + WAE + 1048576) / 4 / 256, 256, 0, stream>>>(x, Wa, Wp, xb);

  gemm_qkv_kernel<<<dim3(3072 / 128, 4096 / 128), 256, 0, stream>>>(xb, wab, ba, qkvb, vtb);
  attn_kernel<<<dim3(16, Bsz * NH), 256, 0, stream>>>(qkvb, vtb, alpha, beta, gamma, yb);
  gemm_proj_kernel<<<dim3(1024 / 128, 4096 / 32), 256, 0, stream>>>(yb, wpb, bp, out);
}

// Round 8
// 204.270 us; speedup vs baseline: 1.2340x; 1.2340x over previous
//
#include <hip/hip_runtime.h>
#include <stdint.h>

#define Bsz  2
#define Tseq 2048
#define Cemb 1024
#define NH   16
#define HD   64

typedef __attribute__((ext_vector_type(8))) __bf16 bf16x8;
typedef __attribute__((ext_vector_type(4))) float  f32x4;
typedef __attribute__((ext_vector_type(8))) unsigned short u16x8;

#define MFMA16(a, b, c) __builtin_amdgcn_mfma_f32_16x16x32_bf16((a), (b), (c), 0, 0, 0)

// fine-grained DMA drain + barrier (vmcnt(N): keep newest N stage-loads in flight)
#define WAIT_BARRIER(N) asm volatile("s_waitcnt vmcnt(" #N ")\n\ts_barrier" ::: "memory")

__device__ __forceinline__ unsigned short f2bf(float f) {
  union { float f; unsigned int u; } v; v.f = f;
  unsigned int u = v.u;
  u += 0x7fffu + ((u >> 16) & 1u);   // RNE; inputs are finite
  return (unsigned short)(u >> 16);
}
__device__ __forceinline__ float bf2f(unsigned short h) {
  union { unsigned int u; float f; } v; v.u = ((unsigned int)h) << 16;
  return v.f;
}
// pack two fp32 -> two bf16 (round-half-up) in one u32: [bf(a) | bf(b)<<16]
__device__ __forceinline__ unsigned int pack_bf2(float a, float b) {
  union { float f; unsigned int u; } va, vb; va.f = a; vb.f = b;
  return __builtin_amdgcn_perm(vb.u + 0x8000u, va.u + 0x8000u, 0x07060302u);
}

typedef __attribute__((address_space(1))) const unsigned int GU;
typedef __attribute__((address_space(3))) unsigned int LU;
__device__ __forceinline__ void load_lds16(const void* g, void* l) {
  __builtin_amdgcn_global_load_lds((GU*)g, (LU*)l, 16, 0, 0);
}

// ---------------- fused cast fp32 -> bf16 for x, W_attn, W_proj ----------------
#define XE  4194304
#define WAE 3145728
__global__ void cast3_kernel(const float* __restrict__ x,
                             const float* __restrict__ wa,
                             const float* __restrict__ wp,
                             unsigned short* __restrict__ out) {
  const int i = (blockIdx.x * blockDim.x + threadIdx.x) * 4;
  const float* src;
  int off;
  if (i < XE) { src = x; off = i; }
  else if (i < XE + WAE) { src = wa; off = i - XE; }
  else { src = wp; off = i - (XE + WAE); }
  const float4 f = *(const float4*)(src + off);
  ushort4 o;
  o.x = f2bf(f.x); o.y = f2bf(f.y); o.z = f2bf(f.z); o.w = f2bf(f.w);
  *(ushort4*)(out + i) = o;
}

// ---------------- qkv GEMM: x[4096,1024] @ W_attn^T[., 3072] + b ----------------
// BK=32. Writes qkv[3][B][H][T][64]; V additionally transposed to
// vt[B][H][64][T] (gathered from the epilogue LDS tile).
__global__ __launch_bounds__(256) void gemm_qkv_kernel(
    const unsigned short* __restrict__ A,
    const unsigned short* __restrict__ Bw,
    const float* __restrict__ bias,
    unsigned short* __restrict__ qkv,
    unsigned short* __restrict__ vt) {
  const int K = Cemb;
  __shared__ unsigned short sA[128 * 32];
  __shared__ unsigned short sB[128 * 32];
  const int tid = threadIdx.x;
  const int wave = tid >> 6, lane = tid & 63;
  const int quad = lane >> 4, lrow = lane & 15;
  const int l7 = lrow & 7;
  const int wm = (wave >> 1) * 64, wn = (wave & 1) * 64;
  const int tileM = blockIdx.y * 128, tileN = blockIdx.x * 128;

  f32x4 acc[4][4];
#pragma unroll
  for (int i = 0; i < 4; ++i)
#pragma unroll
    for (int j = 0; j < 4; ++j) acc[i][j] = (f32x4){0.f, 0.f, 0.f, 0.f};

  for (int k0 = 0; k0 < K; k0 += 32) {
    __syncthreads();
#pragma unroll
    for (int s = 0; s < 2; ++s) {
      const int cid = tid + s * 256;          // 512 chunks of 16B
      const int r = cid >> 2, ko = (cid & 3) * 8;
      load_lds16(&A[(size_t)(tileM + r) * K + k0 + ko], &sA[cid * 8]);
      load_lds16(&Bw[(size_t)(tileN + r) * K + k0 + ko], &sB[cid * 8]);
    }
    __syncthreads();
    bf16x8 af[4], bfm[4];
#pragma unroll
    for (int mt = 0; mt < 4; ++mt)
      af[mt] = *(const bf16x8*)&sA[(wm + mt * 16 + lrow) * 32 + quad * 8];
#pragma unroll
    for (int nt = 0; nt < 4; ++nt)
      bfm[nt] = *(const bf16x8*)&sB[(wn + nt * 16 + lrow) * 32 + quad * 8];
#pragma unroll
    for (int mt = 0; mt < 4; ++mt)
#pragma unroll
      for (int nt = 0; nt < 4; ++nt)
        acc[mt][nt] = MFMA16(af[mt], bfm[nt], acc[mt][nt]);
  }

  // epilogue: transpose through LDS (reuse sA), coalesced 16B stores.
  __syncthreads();
  unsigned short* sEp = sA + wave * 1024;   // 16 rows x 64 cols, swizzled
  float bias_v[4];
#pragma unroll
  for (int nt = 0; nt < 4; ++nt) bias_v[nt] = bias[tileN + wn + nt * 16 + lrow];
  const int gn0 = tileN + wn;               // 64-aligned -> one (part,h) slab
  const int part = gn0 >> 10, h = (gn0 & 1023) >> 6;

#pragma unroll
  for (int mt = 0; mt < 4; ++mt) {
#pragma unroll
    for (int nt = 0; nt < 4; ++nt)
#pragma unroll
      for (int reg = 0; reg < 4; ++reg) {
        const int q = quad * 4 + reg;
        const int ch = (nt * 2 + (lrow >> 3)) ^ (q & 7);
        sEp[q * 64 + ch * 8 + l7] = f2bf(acc[mt][nt][reg] + bias_v[nt]);
      }
    __builtin_amdgcn_wave_barrier();
#pragma unroll
    for (int i = 0; i < 2; ++i) {
      const int c = i * 64 + lane;
      const int r = c >> 3, ch2 = c & 7;
      const u16x8 row = *(const u16x8*)&sEp[r * 64 + ((ch2 ^ (r & 7)) << 3)];
      const int gm = tileM + wm + mt * 16 + r;
      const int bb = gm >> 11, t = gm & 2047;
      *(u16x8*)&qkv[((((size_t)part * Bsz + bb) * NH + h) * Tseq + t) * HD + ch2 * 8] = row;
    }
    if (part == 2) {
      // V^T store: lane owns d=lane, gathers 16 t-values from the LDS column.
      unsigned int w[8];
#pragma unroll
      for (int q = 0; q < 16; q += 2) {
        const unsigned short a0 =
            sEp[q * 64 + (((lane >> 3) ^ (q & 7)) << 3) + (lane & 7)];
        const unsigned short a1 =
            sEp[(q + 1) * 64 + (((lane >> 3) ^ ((q + 1) & 7)) << 3) + (lane & 7)];
        w[q >> 1] = (unsigned int)a0 | ((unsigned int)a1 << 16);
      }
      const int gm0 = tileM + wm + mt * 16;
      const int bb = gm0 >> 11, t0 = gm0 & 2047;
      unsigned short* dst = &vt[(((size_t)bb * NH + h) * HD + lane) * Tseq + t0];
      *(uint4*)(dst) = *(const uint4*)&w[0];
      *(uint4*)(dst + 8) = *(const uint4*)&w[4];
    }
    __builtin_amdgcn_wave_barrier();
  }
}

// ---------------- proj GEMM: y[4096,1024] @ W_proj^T + b -> out fp32 ----------------
// tile 32(M) x 128(N), BK=32, grid (8,128)=1024 blocks -> 4 blocks/CU.
__global__ __launch_bounds__(256) void gemm_proj_kernel(
    const unsigned short* __restrict__ A,
    const unsigned short* __restrict__ Bw,
    const float* __restrict__ bias,
    float* __restrict__ out) {
  const int K = Cemb;
  __shared__ unsigned short sA[32 * 32];
  __shared__ unsigned short sB[128 * 32];
  const int tid = threadIdx.x;
  const int wave = tid >> 6, lane = tid & 63;
  const int quad = lane >> 4, lrow = lane & 15;
  const int wn = wave * 32;
  const int tileM = blockIdx.y * 32, tileN = blockIdx.x * 128;

  f32x4 acc[2][2];
#pragma unroll
  for (int i = 0; i < 2; ++i)
#pragma unroll
    for (int j = 0; j < 2; ++j) acc[i][j] = (f32x4){0.f, 0.f, 0.f, 0.f};

  for (int k0 = 0; k0 < K; k0 += 32) {
    __syncthreads();
    if (tid < 128) {                                     // 128 A-chunks
      const int r = tid >> 2, ko = (tid & 3) * 8;
      load_lds16(&A[(size_t)(tileM + r) * K + k0 + ko], &sA[tid * 8]);
    }
#pragma unroll
    for (int s = 0; s < 2; ++s) {
      const int cB = tid + s * 256;                      // 512 B-chunks
      const int rB = cB >> 2, koB = (cB & 3) * 8;
      load_lds16(&Bw[(size_t)(tileN + rB) * K + k0 + koB], &sB[cB * 8]);
    }
    __syncthreads();
    bf16x8 af[2], bfm[2];
#pragma unroll
    for (int mt = 0; mt < 2; ++mt)
      af[mt] = *(const bf16x8*)&sA[(mt * 16 + lrow) * 32 + quad * 8];
#pragma unroll
    for (int nt = 0; nt < 2; ++nt)
      bfm[nt] = *(const bf16x8*)&sB[(wn + nt * 16 + lrow) * 32 + quad * 8];
#pragma unroll
    for (int mt = 0; mt < 2; ++mt)
#pragma unroll
      for (int nt = 0; nt < 2; ++nt)
        acc[mt][nt] = MFMA16(af[mt], bfm[nt], acc[mt][nt]);
  }

#pragma unroll
  for (int mt = 0; mt < 2; ++mt)
#pragma unroll
    for (int nt = 0; nt < 2; ++nt)
#pragma unroll
      for (int reg = 0; reg < 4; ++reg) {
        const int gm = tileM + mt * 16 + quad * 4 + reg;
        const int gn = tileN + wn + nt * 16 + lrow;
        out[(size_t)gm * Cemb + gn] = acc[mt][nt][reg] + bias[gn];
      }
}

// ---------------- flash attention: transposed-S, dual q-tiles, 3-deep pipeline -
// Round-6 structure (64-key tiles, DMA staging, conflicts=0) + prefetch
// distance 2: 3 LDS buffers, raw s_waitcnt vmcnt(4)+s_barrier keeps the next
// tile's DMA in flight across the barrier (doubles outstanding bytes; the
// round-6 vmcnt(0) drain was the Little's-law bottleneck).
// Each stage_tile = exactly 4 VMEM instructions per wave.
__global__ __launch_bounds__(256) void attn_kernel(
    const unsigned short* __restrict__ qkv,
    const unsigned short* __restrict__ vt,    // [B][H][64][T]
    const float* __restrict__ palpha, const float* __restrict__ pbeta,
    const float* __restrict__ pgamma,
    unsigned short* __restrict__ y) {
  __shared__ unsigned short sK[3][64 * 64];
  __shared__ unsigned short sVt[3][64 * 64];

  const int tid = threadIdx.x;
  const int wave = tid >> 6, lane = tid & 63;
  const int quad = lane >> 4, lrow = lane & 15;
  const int bh = blockIdx.y;
  const int b = bh >> 4, h = bh & 15;

  const size_t partStride = (size_t)Bsz * NH * Tseq * HD;
  const size_t headoff = (size_t)bh * Tseq * HD;
  const unsigned short* Q = qkv + headoff;
  const unsigned short* Kp = qkv + partStride + headoff;
  const unsigned short* Vp = qkv + 2 * partStride + headoff;
  const unsigned short* Vt_g = vt + (size_t)bh * HD * Tseq;

  const float alpha = palpha[0], beta = pbeta[0], gamma = pgamma[0];
  const float SCL = 0.125f * 1.44269504089f;   // /sqrt(d) * log2(e)

  union { unsigned short u[8]; bf16x8 v; } onesU;
#pragma unroll
  for (int j = 0; j < 8; ++j) onesU.u[j] = 0x3F80;  // bf16 1.0
  const bf16x8 onesF = onesU.v;

  const int qtA = blockIdx.x;          // 0..15
  const int qtB = 31 - qtA;            // 16..31
  const int q0A = qtA * 64, q0B = qtB * 64;

  // Q fragments as B operands: B[k=d=quad*8+j][n=q=lrow]
  const int qrowA = q0A + wave * 16 + lrow;
  const int qrowB = q0B + wave * 16 + lrow;
  const bf16x8 bQA0 = *(const bf16x8*)&Q[(size_t)qrowA * HD + quad * 8];
  const bf16x8 bQA1 = *(const bf16x8*)&Q[(size_t)qrowA * HD + 32 + quad * 8];
  const bf16x8 bQB0 = *(const bf16x8*)&Q[(size_t)qrowB * HD + quad * 8];
  const bf16x8 bQB1 = *(const bf16x8*)&Q[(size_t)qrowB * HD + 32 + quad * 8];

  // permuted K-row base: prow = 2*(m&~3)+(m&3) for m=lrow
  const int prow = ((lrow & 12) << 1) | (lrow & 3);

  f32x4 OtA[4], UtA[4], LA, OtB[4], UtB[4], LB;
#pragma unroll
  for (int dt = 0; dt < 4; ++dt) {
    OtA[dt] = (f32x4){0.f, 0.f, 0.f, 0.f};
    UtA[dt] = (f32x4){0.f, 0.f, 0.f, 0.f};
    OtB[dt] = (f32x4){0.f, 0.f, 0.f, 0.f};
    UtB[dt] = (f32x4){0.f, 0.f, 0.f, 0.f};
  }
  LA = (f32x4){0.f, 0.f, 0.f, 0.f};
  LB = (f32x4){0.f, 0.f, 0.f, 0.f};

  // DMA staging (round-6): 512 chunks each for K (row=key) and V^T (row=d).
  // Source-permuted XOR swizzle, lane-linear dests. 4 VMEM instrs per wave.
  auto stage_tile = [&](int it, int buf) {
    const int j0 = it * 64;
#pragma unroll
    for (int s = 0; s < 2; ++s) {
      const int c = tid + s * 256;
      const int r = c >> 3, cc = c & 7;
      const int pk = cc ^ (r & 7) ^ ((r & 16) >> 2);
      load_lds16(&Kp[(size_t)(j0 + r) * HD + pk * 8], &sK[buf][c * 8]);
      load_lds16(&Vt_g[(size_t)r * Tseq + j0 + pk * 8], &sVt[buf][c * 8]);
    }
  };

  stage_tile(0, 0);
  stage_tile(1, 1);

  const int ntiles = qtB + 1;          // >= 17
  for (int it = 0; it < ntiles; ++it) {
    const int cur = it % 3;
    // drain tile `it`'s DMA; keep tile `it+1`'s 4 stage-instructions in flight
    if (it + 1 < ntiles) { WAIT_BARRIER(4); } else { WAIT_BARRIER(0); }
    if (it + 2 < ntiles) stage_tile(it + 2, (it + 2) % 3);

    const unsigned short* K_ = sK[cur];
    const unsigned short* Vt_ = sVt[cur];
    const int j0 = it * 64;
    const bool actA = (it <= qtA);
    const bool diagA = (it == qtA), diagB = (it == qtB);

    // QK^T for both chains; K fragment reads shared.
    unsigned int pkA[4][2], pkB[4][2];
#pragma unroll
    for (int ct = 0; ct < 4; ++ct) {
      const int srow = (ct >> 1) * 32 + (ct & 1) * 4 + prow;
      const int hs = (srow & 7) ^ ((srow & 16) >> 2);
      const bf16x8 a0 = *(const bf16x8*)&K_[srow * 64 + ((quad ^ hs) << 3)];
      const bf16x8 a1 = *(const bf16x8*)&K_[srow * 64 + (((4 + quad) ^ hs) << 3)];
      const int sbase = j0 + (ct >> 1) * 32 + (ct & 1) * 4 + quad * 8;

      f32x4 sB = (f32x4){0.f, 0.f, 0.f, 0.f};
      sB = MFMA16(a0, bQB0, sB);
      sB = MFMA16(a1, bQB1, sB);
      float pB[4];
      if (diagB) {
#pragma unroll
        for (int reg = 0; reg < 4; ++reg)
          pB[reg] = exp2f((sbase + reg > qrowB) ? -1e30f : sB[reg] * SCL);
      } else {
#pragma unroll
        for (int reg = 0; reg < 4; ++reg) pB[reg] = exp2f(sB[reg] * SCL);
      }
      pkB[ct][0] = pack_bf2(pB[0], pB[1]);
      pkB[ct][1] = pack_bf2(pB[2], pB[3]);

      if (actA) {
        f32x4 sA = (f32x4){0.f, 0.f, 0.f, 0.f};
        sA = MFMA16(a0, bQA0, sA);
        sA = MFMA16(a1, bQA1, sA);
        float pA[4];
        if (diagA) {
#pragma unroll
          for (int reg = 0; reg < 4; ++reg)
            pA[reg] = exp2f((sbase + reg > qrowA) ? -1e30f : sA[reg] * SCL);
        } else {
#pragma unroll
          for (int reg = 0; reg < 4; ++reg) pA[reg] = exp2f(sA[reg] * SCL);
        }
        pkA[ct][0] = pack_bf2(pA[0], pA[1]);
        pkA[ct][1] = pack_bf2(pA[2], pA[3]);
      }
    }

    union { unsigned int w[4]; bf16x8 v; } tu;
    tu.w[0] = pkB[0][0]; tu.w[1] = pkB[0][1]; tu.w[2] = pkB[1][0]; tu.w[3] = pkB[1][1];
    const bf16x8 P1B = tu.v;
    tu.w[0] = pkB[2][0]; tu.w[1] = pkB[2][1]; tu.w[2] = pkB[3][0]; tu.w[3] = pkB[3][1];
    const bf16x8 P2B = tu.v;
    bf16x8 P1A = onesF, P2A = onesF;
    if (actA) {
      tu.w[0] = pkA[0][0]; tu.w[1] = pkA[0][1]; tu.w[2] = pkA[1][0]; tu.w[3] = pkA[1][1];
      P1A = tu.v;
      tu.w[0] = pkA[2][0]; tu.w[1] = pkA[2][1]; tu.w[2] = pkA[3][0]; tu.w[3] = pkA[3][1];
      P2A = tu.v;
    }

    LB = MFMA16(onesF, P1B, LB);
    LB = MFMA16(onesF, P2B, LB);
    if (actA) {
      LA = MFMA16(onesF, P1A, LA);
      LA = MFMA16(onesF, P2A, LA);
    }

    // masked-ones B operands for U
    bf16x8 u1B = onesF, u2B = onesF, u1A = onesF, u2A = onesF;
    if (diagB) {
      union { unsigned short u[8]; bf16x8 v; } m0, m1;
#pragma unroll
      for (int jj = 0; jj < 8; ++jj) {
        m0.u[jj] = (j0 + quad * 8 + jj) <= qrowB ? (unsigned short)0x3F80 : (unsigned short)0;
        m1.u[jj] = (j0 + 32 + quad * 8 + jj) <= qrowB ? (unsigned short)0x3F80 : (unsigned short)0;
      }
      u1B = m0.v; u2B = m1.v;
    }
    if (actA && diagA) {
      union { unsigned short u[8]; bf16x8 v; } m0, m1;
#pragma unroll
      for (int jj = 0; jj < 8; ++jj) {
        m0.u[jj] = (j0 + quad * 8 + jj) <= qrowA ? (unsigned short)0x3F80 : (unsigned short)0;
        m1.u[jj] = (j0 + 32 + quad * 8 + jj) <= qrowA ? (unsigned short)0x3F80 : (unsigned short)0;
      }
      u1A = m0.v; u2A = m1.v;
    }

    // PV + U for both chains; V fragment reads shared.
#pragma unroll
    for (int dt = 0; dt < 4; ++dt) {
      const int vr = dt * 16 + lrow;
      const int hvr = (vr & 7) ^ ((vr & 16) >> 2);
      const bf16x8 av0 = *(const bf16x8*)&Vt_[vr * 64 + ((quad ^ hvr) << 3)];
      const bf16x8 av1 = *(const bf16x8*)&Vt_[vr * 64 + (((4 + quad) ^ hvr) << 3)];
      OtB[dt] = MFMA16(av0, P1B, OtB[dt]);
      OtB[dt] = MFMA16(av1, P2B, OtB[dt]);
      UtB[dt] = MFMA16(av0, u1B, UtB[dt]);
      UtB[dt] = MFMA16(av1, u2B, UtB[dt]);
      if (actA) {
        OtA[dt] = MFMA16(av0, P1A, OtA[dt]);
        OtA[dt] = MFMA16(av1, P2A, OtA[dt]);
        UtA[dt] = MFMA16(av0, u1A, UtA[dt]);
        UtA[dt] = MFMA16(av1, u2A, UtA[dt]);
      }
    }
  }

  // epilogue: thread owns q-row, d = dt*16+quad*4+reg
  auto epilogue = [&](const f32x4* Ot, const f32x4* Ut, const f32x4& L, int qrow) {
    const float bl = beta / L[0];
    const float gi = gamma / (float)(qrow + 1);
    const size_t ybase = ((size_t)b * Tseq + qrow) * Cemb + h * HD;
#pragma unroll
    for (int dt = 0; dt < 4; ++dt) {
      const int d0 = dt * 16 + quad * 4;
      const ushort4 vv4 = *(const ushort4*)&Vp[(size_t)qrow * HD + d0];
      const unsigned short vu[4] = {vv4.x, vv4.y, vv4.z, vv4.w};
      ushort4 o;
      unsigned short* op = (unsigned short*)&o;
#pragma unroll
      for (int reg = 0; reg < 4; ++reg) {
        const float yv = bl * Ot[dt][reg] + alpha * bf2f(vu[reg]) - gi * Ut[dt][reg];
        op[reg] = f2bf(yv);
      }
      *(ushort4*)&y[ybase + d0] = o;
    }
  };
  epilogue(OtA, UtA, LA, qrowA);
  epilogue(OtB, UtB, LB, qrowB);
}

// ---------------- host launch ----------------
extern "C" void kernel_launch(void* const* d_in, const int* in_sizes, int n_in,
                              void* d_out, int out_size, void* d_ws, size_t ws_size,
                              hipStream_t stream) {
  const float* x  = (const float*)d_in[0];
  const float* Wa = (const float*)d_in[1];
  const float* ba = (const float*)d_in[2];
  const float* Wp = (const float*)d_in[3];
  const float* bp = (const float*)d_in[4];
  const float* alpha = (const float*)d_in[5];
  const float* beta  = (const float*)d_in[6];
  const float* gamma = (const float*)d_in[7];
  float* out = (float*)d_out;

  unsigned short* ws = (unsigned short*)d_ws;
  unsigned short* xb   = ws;                                   // 4M bf16
  unsigned short* wab  = xb + (size_t)XE;                      // 3M
  unsigned short* wpb  = wab + (size_t)WAE;                    // 1M
  unsigned short* qkvb = wpb + (size_t)1024 * 1024;            // 12M
  unsigned short* yb   = qkvb + (size_t)3 * Bsz * NH * Tseq * HD;  // 4M
  unsigned short* vtb  = yb + (size_t)Bsz * Tseq * Cemb;       // 4M (V^T)

  cast3_kernel<<<(XE + WAE + 1048576) / 4 / 256, 256, 0, stream>>>(x, Wa, Wp, xb);

  gemm_qkv_kernel<<<dim3(3072 / 128, 4096 / 128), 256, 0, stream>>>(xb, wab, ba, qkvb, vtb);
  attn_kernel<<<dim3(16, Bsz * NH), 256, 0, stream>>>(qkvb, vtb, alpha, beta, gamma, yb);
  gemm_proj_kernel<<<dim3(1024 / 128, 4096 / 32), 256, 0, stream>>>(yb, wpb, bp, out);
}

// Round 9
// 197.725 us; speedup vs baseline: 1.2748x; 1.0331x over previous
//
#include <hip/hip_runtime.h>
#include <stdint.h>

#define Bsz  2
#define Tseq 2048
#define Cemb 1024
#define NH   16
#define HD   64

typedef __attribute__((ext_vector_type(8))) __bf16 bf16x8;
typedef __attribute__((ext_vector_type(4))) float  f32x4;
typedef __attribute__((ext_vector_type(8))) unsigned short u16x8;

#define MFMA16(a, b, c) __builtin_amdgcn_mfma_f32_16x16x32_bf16((a), (b), (c), 0, 0, 0)

__device__ __forceinline__ unsigned short f2bf(float f) {
  union { float f; unsigned int u; } v; v.f = f;
  unsigned int u = v.u;
  u += 0x7fffu + ((u >> 16) & 1u);   // RNE; inputs are finite
  return (unsigned short)(u >> 16);
}
__device__ __forceinline__ float bf2f(unsigned short h) {
  union { unsigned int u; float f; } v; v.u = ((unsigned int)h) << 16;
  return v.f;
}
// pack two fp32 -> two bf16 (round-half-up) in one u32: [bf(a) | bf(b)<<16]
__device__ __forceinline__ unsigned int pack_bf2(float a, float b) {
  union { float f; unsigned int u; } va, vb; va.f = a; vb.f = b;
  return __builtin_amdgcn_perm(vb.u + 0x8000u, va.u + 0x8000u, 0x07060302u);
}

typedef __attribute__((address_space(1))) const unsigned int GU;
typedef __attribute__((address_space(3))) unsigned int LU;
__device__ __forceinline__ void load_lds16(const void* g, void* l) {
  __builtin_amdgcn_global_load_lds((GU*)g, (LU*)l, 16, 0, 0);
}

// ---------------- fused cast fp32 -> bf16 for x, W_attn, W_proj ----------------
#define XE  4194304
#define WAE 3145728
__global__ void cast3_kernel(const float* __restrict__ x,
                             const float* __restrict__ wa,
                             const float* __restrict__ wp,
                             unsigned short* __restrict__ out) {
  const int i = (blockIdx.x * blockDim.x + threadIdx.x) * 4;
  const float* src;
  int off;
  if (i < XE) { src = x; off = i; }
  else if (i < XE + WAE) { src = wa; off = i - XE; }
  else { src = wp; off = i - (XE + WAE); }
  const float4 f = *(const float4*)(src + off);
  ushort4 o;
  o.x = f2bf(f.x); o.y = f2bf(f.y); o.z = f2bf(f.z); o.w = f2bf(f.w);
  *(ushort4*)(out + i) = o;
}

// ---------------- qkv GEMM: x[4096,1024] @ W_attn^T[., 3072] + b ----------------
// BK=32. Writes qkv[3][B][H][T][64] with the Q part PRESCALED by 1/8 (exact in
// bf16; removes the score scaling + lets attn use natural-base __expf).
// V additionally transposed to vt[B][H][64][T].
__global__ __launch_bounds__(256) void gemm_qkv_kernel(
    const unsigned short* __restrict__ A,
    const unsigned short* __restrict__ Bw,
    const float* __restrict__ bias,
    unsigned short* __restrict__ qkv,
    unsigned short* __restrict__ vt) {
  const int K = Cemb;
  __shared__ unsigned short sA[128 * 32];
  __shared__ unsigned short sB[128 * 32];
  const int tid = threadIdx.x;
  const int wave = tid >> 6, lane = tid & 63;
  const int quad = lane >> 4, lrow = lane & 15;
  const int l7 = lrow & 7;
  const int wm = (wave >> 1) * 64, wn = (wave & 1) * 64;
  const int tileM = blockIdx.y * 128, tileN = blockIdx.x * 128;

  f32x4 acc[4][4];
#pragma unroll
  for (int i = 0; i < 4; ++i)
#pragma unroll
    for (int j = 0; j < 4; ++j) acc[i][j] = (f32x4){0.f, 0.f, 0.f, 0.f};

  for (int k0 = 0; k0 < K; k0 += 32) {
    __syncthreads();
#pragma unroll
    for (int s = 0; s < 2; ++s) {
      const int cid = tid + s * 256;          // 512 chunks of 16B
      const int r = cid >> 2, ko = (cid & 3) * 8;
      load_lds16(&A[(size_t)(tileM + r) * K + k0 + ko], &sA[cid * 8]);
      load_lds16(&Bw[(size_t)(tileN + r) * K + k0 + ko], &sB[cid * 8]);
    }
    __syncthreads();
    bf16x8 af[4], bfm[4];
#pragma unroll
    for (int mt = 0; mt < 4; ++mt)
      af[mt] = *(const bf16x8*)&sA[(wm + mt * 16 + lrow) * 32 + quad * 8];
#pragma unroll
    for (int nt = 0; nt < 4; ++nt)
      bfm[nt] = *(const bf16x8*)&sB[(wn + nt * 16 + lrow) * 32 + quad * 8];
#pragma unroll
    for (int mt = 0; mt < 4; ++mt)
#pragma unroll
      for (int nt = 0; nt < 4; ++nt)
        acc[mt][nt] = MFMA16(af[mt], bfm[nt], acc[mt][nt]);
  }

  // epilogue: transpose through LDS (reuse sA), coalesced 16B stores.
  __syncthreads();
  unsigned short* sEp = sA + wave * 1024;   // 16 rows x 64 cols, swizzled
  float bias_v[4];
#pragma unroll
  for (int nt = 0; nt < 4; ++nt) bias_v[nt] = bias[tileN + wn + nt * 16 + lrow];
  const int gn0 = tileN + wn;               // 64-aligned -> one (part,h) slab
  const int part = gn0 >> 10, h = (gn0 & 1023) >> 6;
  const float qscl = (part == 0) ? 0.125f : 1.0f;   // fold 1/sqrt(d) into Q (exact)

#pragma unroll
  for (int mt = 0; mt < 4; ++mt) {
#pragma unroll
    for (int nt = 0; nt < 4; ++nt)
#pragma unroll
      for (int reg = 0; reg < 4; ++reg) {
        const int q = quad * 4 + reg;
        const int ch = (nt * 2 + (lrow >> 3)) ^ (q & 7);
        sEp[q * 64 + ch * 8 + l7] = f2bf((acc[mt][nt][reg] + bias_v[nt]) * qscl);
      }
    __builtin_amdgcn_wave_barrier();
#pragma unroll
    for (int i = 0; i < 2; ++i) {
      const int c = i * 64 + lane;
      const int r = c >> 3, ch2 = c & 7;
      const u16x8 row = *(const u16x8*)&sEp[r * 64 + ((ch2 ^ (r & 7)) << 3)];
      const int gm = tileM + wm + mt * 16 + r;
      const int bb = gm >> 11, t = gm & 2047;
      *(u16x8*)&qkv[((((size_t)part * Bsz + bb) * NH + h) * Tseq + t) * HD + ch2 * 8] = row;
    }
    if (part == 2) {
      // V^T store: lane owns d=lane, gathers 16 t-values from the LDS column.
      unsigned int w[8];
#pragma unroll
      for (int q = 0; q < 16; q += 2) {
        const unsigned short a0 =
            sEp[q * 64 + (((lane >> 3) ^ (q & 7)) << 3) + (lane & 7)];
        const unsigned short a1 =
            sEp[(q + 1) * 64 + (((lane >> 3) ^ ((q + 1) & 7)) << 3) + (lane & 7)];
        w[q >> 1] = (unsigned int)a0 | ((unsigned int)a1 << 16);
      }
      const int gm0 = tileM + wm + mt * 16;
      const int bb = gm0 >> 11, t0 = gm0 & 2047;
      unsigned short* dst = &vt[(((size_t)bb * NH + h) * HD + lane) * Tseq + t0];
      *(uint4*)(dst) = *(const uint4*)&w[0];
      *(uint4*)(dst + 8) = *(const uint4*)&w[4];
    }
    __builtin_amdgcn_wave_barrier();
  }
}

// ---------------- proj GEMM: y[4096,1024] @ W_proj^T + b -> out fp32 ----------------
// tile 32(M) x 128(N), BK=32, grid (8,128)=1024 blocks -> 4 blocks/CU.
__global__ __launch_bounds__(256) void gemm_proj_kernel(
    const unsigned short* __restrict__ A,
    const unsigned short* __restrict__ Bw,
    const float* __restrict__ bias,
    float* __restrict__ out) {
  const int K = Cemb;
  __shared__ unsigned short sA[32 * 32];
  __shared__ unsigned short sB[128 * 32];
  const int tid = threadIdx.x;
  const int wave = tid >> 6, lane = tid & 63;
  const int quad = lane >> 4, lrow = lane & 15;
  const int wn = wave * 32;
  const int tileM = blockIdx.y * 32, tileN = blockIdx.x * 128;

  f32x4 acc[2][2];
#pragma unroll
  for (int i = 0; i < 2; ++i)
#pragma unroll
    for (int j = 0; j < 2; ++j) acc[i][j] = (f32x4){0.f, 0.f, 0.f, 0.f};

  for (int k0 = 0; k0 < K; k0 += 32) {
    __syncthreads();
    if (tid < 128) {                                     // 128 A-chunks
      const int r = tid >> 2, ko = (tid & 3) * 8;
      load_lds16(&A[(size_t)(tileM + r) * K + k0 + ko], &sA[tid * 8]);
    }
#pragma unroll
    for (int s = 0; s < 2; ++s) {
      const int cB = tid + s * 256;                      // 512 B-chunks
      const int rB = cB >> 2, koB = (cB & 3) * 8;
      load_lds16(&Bw[(size_t)(tileN + rB) * K + k0 + koB], &sB[cB * 8]);
    }
    __syncthreads();
    bf16x8 af[2], bfm[2];
#pragma unroll
    for (int mt = 0; mt < 2; ++mt)
      af[mt] = *(const bf16x8*)&sA[(mt * 16 + lrow) * 32 + quad * 8];
#pragma unroll
    for (int nt = 0; nt < 2; ++nt)
      bfm[nt] = *(const bf16x8*)&sB[(wn + nt * 16 + lrow) * 32 + quad * 8];
#pragma unroll
    for (int mt = 0; mt < 2; ++mt)
#pragma unroll
      for (int nt = 0; nt < 2; ++nt)
        acc[mt][nt] = MFMA16(af[mt], bfm[nt], acc[mt][nt]);
  }

#pragma unroll
  for (int mt = 0; mt < 2; ++mt)
#pragma unroll
    for (int nt = 0; nt < 2; ++nt)
#pragma unroll
      for (int reg = 0; reg < 4; ++reg) {
        const int gm = tileM + mt * 16 + quad * 4 + reg;
        const int gn = tileN + wn + nt * 16 + lrow;
        out[(size_t)gm * Cemb + gn] = acc[mt][nt][reg] + bias[gn];
      }
}

// ---------------- flash attention: transposed-S, dual q-tiles, native exp ------
// Round-6 structure (best measured: double-buffered DMA staging, conflicts=0).
// Q arrives prescaled by 1/8, so P = __expf(S) -- native v_exp_f32, not the
// OCML exp2 polynomial that was ~480 VALU instrs/tile-unit in rounds 3-8.
__global__ __launch_bounds__(256) void attn_kernel(
    const unsigned short* __restrict__ qkv,
    const unsigned short* __restrict__ vt,    // [B][H][64][T]
    const float* __restrict__ palpha, const float* __restrict__ pbeta,
    const float* __restrict__ pgamma,
    unsigned short* __restrict__ y) {
  __shared__ unsigned short sK[2][64 * 64];
  __shared__ unsigned short sVt[2][64 * 64];

  const int tid = threadIdx.x;
  const int wave = tid >> 6, lane = tid & 63;
  const int quad = lane >> 4, lrow = lane & 15;
  const int bh = blockIdx.y;
  const int b = bh >> 4, h = bh & 15;

  const size_t partStride = (size_t)Bsz * NH * Tseq * HD;
  const size_t headoff = (size_t)bh * Tseq * HD;
  const unsigned short* Q = qkv + headoff;
  const unsigned short* Kp = qkv + partStride + headoff;
  const unsigned short* Vp = qkv + 2 * partStride + headoff;
  const unsigned short* Vt_g = vt + (size_t)bh * HD * Tseq;

  const float alpha = palpha[0], beta = pbeta[0], gamma = pgamma[0];

  union { unsigned short u[8]; bf16x8 v; } onesU;
#pragma unroll
  for (int j = 0; j < 8; ++j) onesU.u[j] = 0x3F80;  // bf16 1.0
  const bf16x8 onesF = onesU.v;

  const int qtA = blockIdx.x;          // 0..15
  const int qtB = 31 - qtA;            // 16..31
  const int q0A = qtA * 64, q0B = qtB * 64;

  // Q fragments as B operands: B[k=d=quad*8+j][n=q=lrow]
  const int qrowA = q0A + wave * 16 + lrow;
  const int qrowB = q0B + wave * 16 + lrow;
  const bf16x8 bQA0 = *(const bf16x8*)&Q[(size_t)qrowA * HD + quad * 8];
  const bf16x8 bQA1 = *(const bf16x8*)&Q[(size_t)qrowA * HD + 32 + quad * 8];
  const bf16x8 bQB0 = *(const bf16x8*)&Q[(size_t)qrowB * HD + quad * 8];
  const bf16x8 bQB1 = *(const bf16x8*)&Q[(size_t)qrowB * HD + 32 + quad * 8];

  // permuted K-row base: prow = 2*(m&~3)+(m&3) for m=lrow
  const int prow = ((lrow & 12) << 1) | (lrow & 3);

  f32x4 OtA[4], UtA[4], LA, OtB[4], UtB[4], LB;
#pragma unroll
  for (int dt = 0; dt < 4; ++dt) {
    OtA[dt] = (f32x4){0.f, 0.f, 0.f, 0.f};
    UtA[dt] = (f32x4){0.f, 0.f, 0.f, 0.f};
    OtB[dt] = (f32x4){0.f, 0.f, 0.f, 0.f};
    UtB[dt] = (f32x4){0.f, 0.f, 0.f, 0.f};
  }
  LA = (f32x4){0.f, 0.f, 0.f, 0.f};
  LB = (f32x4){0.f, 0.f, 0.f, 0.f};

  // DMA staging: 512 chunks each for K (row=key) and V^T (row=d).
  // Source-permuted XOR swizzle, lane-linear dests (DMA-legal).
  auto stage_tile = [&](int it, int buf) {
    const int j0 = it * 64;
#pragma unroll
    for (int s = 0; s < 2; ++s) {
      const int c = tid + s * 256;
      const int r = c >> 3, cc = c & 7;
      const int pk = cc ^ (r & 7) ^ ((r & 16) >> 2);
      load_lds16(&Kp[(size_t)(j0 + r) * HD + pk * 8], &sK[buf][c * 8]);
      load_lds16(&Vt_g[(size_t)r * Tseq + j0 + pk * 8], &sVt[buf][c * 8]);
    }
  };

  stage_tile(0, 0);

  const int ntiles = qtB + 1;
  for (int it = 0; it < ntiles; ++it) {
    const int cur = it & 1;
    __syncthreads();                 // drains DMA for tile `it`, fences readers
    if (it + 1 < ntiles) stage_tile(it + 1, (it + 1) & 1);

    const unsigned short* K_ = sK[cur];
    const unsigned short* Vt_ = sVt[cur];
    const int j0 = it * 64;
    const bool actA = (it <= qtA);
    const bool diagA = (it == qtA), diagB = (it == qtB);

    // QK^T for both chains; K fragment reads shared. P = __expf(S) (native).
    unsigned int pkA[4][2], pkB[4][2];
#pragma unroll
    for (int ct = 0; ct < 4; ++ct) {
      const int srow = (ct >> 1) * 32 + (ct & 1) * 4 + prow;
      const int hs = (srow & 7) ^ ((srow & 16) >> 2);
      const bf16x8 a0 = *(const bf16x8*)&K_[srow * 64 + ((quad ^ hs) << 3)];
      const bf16x8 a1 = *(const bf16x8*)&K_[srow * 64 + (((4 + quad) ^ hs) << 3)];
      const int sbase = j0 + (ct >> 1) * 32 + (ct & 1) * 4 + quad * 8;

      f32x4 sB = (f32x4){0.f, 0.f, 0.f, 0.f};
      sB = MFMA16(a0, bQB0, sB);
      sB = MFMA16(a1, bQB1, sB);
      float pB[4];
      if (diagB) {
#pragma unroll
        for (int reg = 0; reg < 4; ++reg)
          pB[reg] = __expf((sbase + reg > qrowB) ? -1e30f : sB[reg]);
      } else {
#pragma unroll
        for (int reg = 0; reg < 4; ++reg) pB[reg] = __expf(sB[reg]);
      }
      pkB[ct][0] = pack_bf2(pB[0], pB[1]);
      pkB[ct][1] = pack_bf2(pB[2], pB[3]);

      if (actA) {
        f32x4 sA = (f32x4){0.f, 0.f, 0.f, 0.f};
        sA = MFMA16(a0, bQA0, sA);
        sA = MFMA16(a1, bQA1, sA);
        float pA[4];
        if (diagA) {
#pragma unroll
          for (int reg = 0; reg < 4; ++reg)
            pA[reg] = __expf((sbase + reg > qrowA) ? -1e30f : sA[reg]);
        } else {
#pragma unroll
          for (int reg = 0; reg < 4; ++reg) pA[reg] = __expf(sA[reg]);
        }
        pkA[ct][0] = pack_bf2(pA[0], pA[1]);
        pkA[ct][1] = pack_bf2(pA[2], pA[3]);
      }
    }

    union { unsigned int w[4]; bf16x8 v; } tu;
    tu.w[0] = pkB[0][0]; tu.w[1] = pkB[0][1]; tu.w[2] = pkB[1][0]; tu.w[3] = pkB[1][1];
    const bf16x8 P1B = tu.v;
    tu.w[0] = pkB[2][0]; tu.w[1] = pkB[2][1]; tu.w[2] = pkB[3][0]; tu.w[3] = pkB[3][1];
    const bf16x8 P2B = tu.v;
    bf16x8 P1A = onesF, P2A = onesF;
    if (actA) {
      tu.w[0] = pkA[0][0]; tu.w[1] = pkA[0][1]; tu.w[2] = pkA[1][0]; tu.w[3] = pkA[1][1];
      P1A = tu.v;
      tu.w[0] = pkA[2][0]; tu.w[1] = pkA[2][1]; tu.w[2] = pkA[3][0]; tu.w[3] = pkA[3][1];
      P2A = tu.v;
    }

    LB = MFMA16(onesF, P1B, LB);
    LB = MFMA16(onesF, P2B, LB);
    if (actA) {
      LA = MFMA16(onesF, P1A, LA);
      LA = MFMA16(onesF, P2A, LA);
    }

    // masked-ones B operands for U
    bf16x8 u1B = onesF, u2B = onesF, u1A = onesF, u2A = onesF;
    if (diagB) {
      union { unsigned short u[8]; bf16x8 v; } m0, m1;
#pragma unroll
      for (int jj = 0; jj < 8; ++jj) {
        m0.u[jj] = (j0 + quad * 8 + jj) <= qrowB ? (unsigned short)0x3F80 : (unsigned short)0;
        m1.u[jj] = (j0 + 32 + quad * 8 + jj) <= qrowB ? (unsigned short)0x3F80 : (unsigned short)0;
      }
      u1B = m0.v; u2B = m1.v;
    }
    if (actA && diagA) {
      union { unsigned short u[8]; bf16x8 v; } m0, m1;
#pragma unroll
      for (int jj = 0; jj < 8; ++jj) {
        m0.u[jj] = (j0 + quad * 8 + jj) <= qrowA ? (unsigned short)0x3F80 : (unsigned short)0;
        m1.u[jj] = (j0 + 32 + quad * 8 + jj) <= qrowA ? (unsigned short)0x3F80 : (unsigned short)0;
      }
      u1A = m0.v; u2A = m1.v;
    }

    // PV + U for both chains; V fragment reads shared.
#pragma unroll
    for (int dt = 0; dt < 4; ++dt) {
      const int vr = dt * 16 + lrow;
      const int hvr = (vr & 7) ^ ((vr & 16) >> 2);
      const bf16x8 av0 = *(const bf16x8*)&Vt_[vr * 64 + ((quad ^ hvr) << 3)];
      const bf16x8 av1 = *(const bf16x8*)&Vt_[vr * 64 + (((4 + quad) ^ hvr) << 3)];
      OtB[dt] = MFMA16(av0, P1B, OtB[dt]);
      OtB[dt] = MFMA16(av1, P2B, OtB[dt]);
      UtB[dt] = MFMA16(av0, u1B, UtB[dt]);
      UtB[dt] = MFMA16(av1, u2B, UtB[dt]);
      if (actA) {
        OtA[dt] = MFMA16(av0, P1A, OtA[dt]);
        OtA[dt] = MFMA16(av1, P2A, OtA[dt]);
        UtA[dt] = MFMA16(av0, u1A, UtA[dt]);
        UtA[dt] = MFMA16(av1, u2A, UtA[dt]);
      }
    }
  }

  // epilogue: thread owns q-row, d = dt*16+quad*4+reg
  auto epilogue = [&](const f32x4* Ot, const f32x4* Ut, const f32x4& L, int qrow) {
    const float bl = beta / L[0];
    const float gi = gamma / (float)(qrow + 1);
    const size_t ybase = ((size_t)b * Tseq + qrow) * Cemb + h * HD;
#pragma unroll
    for (int dt = 0; dt < 4; ++dt) {
      const int d0 = dt * 16 + quad * 4;
      const ushort4 vv4 = *(const ushort4*)&Vp[(size_t)qrow * HD + d0];
      const unsigned short vu[4] = {vv4.x, vv4.y, vv4.z, vv4.w};
      ushort4 o;
      unsigned short* op = (unsigned short*)&o;
#pragma unroll
      for (int reg = 0; reg < 4; ++reg) {
        const float yv = bl * Ot[dt][reg] + alpha * bf2f(vu[reg]) - gi * Ut[dt][reg];
        op[reg] = f2bf(yv);
      }
      *(ushort4*)&y[ybase + d0] = o;
    }
  };
  epilogue(OtA, UtA, LA, qrowA);
  epilogue(OtB, UtB, LB, qrowB);
}

// ---------------- host launch ----------------
extern "C" void kernel_launch(void* const* d_in, const int* in_sizes, int n_in,
                              void* d_out, int out_size, void* d_ws, size_t ws_size,
                              hipStream_t stream) {
  const float* x  = (const float*)d_in[0];
  const float* Wa = (const float*)d_in[1];
  const float* ba = (const float*)d_in[2];
  const float* Wp = (const float*)d_in[3];
  const float* bp = (const float*)d_in[4];
  const float* alpha = (const float*)d_in[5];
  const float* beta  = (const float*)d_in[6];
  const float* gamma = (const float*)d_in[7];
  float* out = (float*)d_out;

  unsigned short* ws = (unsigned short*)d_ws;
  unsigned short* xb   = ws;                                   // 4M bf16
  unsigned short* wab  = xb + (size_t)XE;                      // 3M
  unsigned short* wpb  = wab + (size_t)WAE;                    // 1M
  unsigned short* qkvb = wpb + (size_t)1024 * 1024;            // 12M
  unsigned short* yb   = qkvb + (size_t)3 * Bsz * NH * Tseq * HD;  // 4M
  unsigned short* vtb  = yb + (size_t)Bsz * Tseq * Cemb;       // 4M (V^T)

  cast3_kernel<<<(XE + WAE + 1048576) / 4 / 256, 256, 0, stream>>>(x, Wa, Wp, xb);

  gemm_qkv_kernel<<<dim3(3072 / 128, 4096 / 128), 256, 0, stream>>>(xb, wab, ba, qkvb, vtb);
  attn_kernel<<<dim3(16, Bsz * NH), 256, 0, stream>>>(qkvb, vtb, alpha, beta, gamma, yb);
  gemm_proj_kernel<<<dim3(1024 / 128, 4096 / 32), 256, 0, stream>>>(yb, wpb, bp, out);
}